// Round 9
// baseline (192.209 us; speedup 1.0000x reference)
//
#include <hip/hip_runtime.h>

// Problem constants
static constexpr int NB   = 128;   // batch
static constexpr int NCIN = 64;    // input channels
static constexpr int NG   = 8;     // groups
static constexpr int NH   = 14;    // spatial
static constexpr int NP   = 16;    // mixed width
static constexpr int HH   = NH * NH;       // 196
static constexpr int LROW = 20;    // padded t4s row (l in [-2,17])

// LDS layout (float offsets). Phase B reads x directly from global.
// NO output staging anymore: conv accumulators are stored straight to global
// (each thread owns contiguous 56 B runs; L2 merges across the same-XCD
// o-blocks thanks to the R8 swizzle). Exactly one __syncthreads in the kernel.
static constexpr int OFF_T4 = 0;      // [8][16][20] = 2560
static constexpr int OFF_W2 = 2560;   // [8][5][32]  = 1280
static constexpr int OFF_WC = 3840;   // [2][8][32]  =  512
static constexpr int LDS_FLOATS = 4352;   // 17,408 B -> 8 blocks/CU (wave-capped)

// FMA quarter: 16 j-values from reg buffer `buf`, wmix rows qb..qb+15 via s_load
#define FMAQ(buf, qb)                                                          \
    do {                                                                       \
        _Pragma("unroll")                                                      \
        for (int j4 = 0; j4 < 4; j4++) {                                       \
            _Pragma("unroll")                                                  \
            for (int pp = 0; pp < 8; pp++) {                                   \
                const int p_ = p0 + pp; /* wave-uniform -> s_load */           \
                am[pp] += buf[j4 * 4 + 0] * wmix[((qb) + j4 * 4 + 0) * NP + p_]\
                        + buf[j4 * 4 + 1] * wmix[((qb) + j4 * 4 + 1) * NP + p_]\
                        + buf[j4 * 4 + 2] * wmix[((qb) + j4 * 4 + 2) * NP + p_]\
                        + buf[j4 * 4 + 3] * wmix[((qb) + j4 * 4 + 3) * NP + p_];\
            }                                                                  \
        }                                                                      \
    } while (0)

// ---------------------------------------------------------------------------
// Fully fused kernel. block = (b, o), 256 threads, 8 blocks/CU resident.
//   - XCD-aware bid->(b,o) swizzle (verified R8): all 14 o-blocks of a batch
//     share one XCD/L2 so their 56 B out-row pieces merge into full lines.
//   - phase B (mix): thread owns one gl + wave-uniform p-half; 64 x[j] loads
//     direct from global, reg-double-buffered; wmix via s_load. No barriers.
//   - conv: verified 5-tap structure, unchanged.
//   - R9 change (ONLY change vs verified R8): direct register->global
//     writeout. Thread (p,jh) holds channels c=(jb+jj)*16+p as contiguous
//     14-float runs in acc -> 7 float2 stores each (8B-aligned: all offset
//     terms even). Deletes the LDS staging, 4 barriers, and the c*15-map
//     bank conflicts; byte-level HBM write traffic is unchanged (L2 merge).
// ---------------------------------------------------------------------------
__global__ __launch_bounds__(256, 8) void fused_kernel(const float* __restrict__ x,
                                                       const float* __restrict__ wconv,
                                                       const float* __restrict__ wmix,
                                                       float* __restrict__ out) {
    __shared__ __align__(16) float lds[LDS_FLOATS];
    float* t4s = lds + OFF_T4;
    float* w2s = lds + OFF_W2;
    float* wcs = lds + OFF_WC;

    const int tid = threadIdx.x;
    // ---- XCD-aware decode: all 14 o-blocks of a given b share bid%8 ----
    const int bid = blockIdx.x;                  // 0..1791
    const int xcd = bid & 7;
    const int t8  = bid >> 3;                    // 0..223
    const int o   = t8 % NH;
    const int b   = xcd + 8 * (t8 / NH);
    const int o_src = (o + NH - 1) % NH;

    // ---- wconv loads (9 per thread, coalesced); consumed before phase B ----
    const int gW = tid >> 5, jW = tid & 31;
    float wv9[9];
    {
        const float* wp = wconv + (size_t)(gW * 9) * 32 + jW;
#pragma unroll
        for (int t = 0; t < 9; t++) wv9[t] = wp[t * 32];
    }

    // ---- phase-B geometry: thread = (gl, p-half) ----
    const int  lane128 = tid & 127;
    const bool xact    = lane128 < 112;
    const int  gS      = lane128 / 14;
    const int  lS      = lane128 % 14;
    const int  p0      = __builtin_amdgcn_readfirstlane((tid >> 7) << 3);  // 0/8
    const float* xg    = x + (size_t)b * (NCIN * NG * HH) + (size_t)gS * HH
                           + o_src * NH + lS;

    // issue x quarter 0 (j = 0..15) while w2s/pads execute
    float xq0[16], xq1[16];
    if (xact) {
#pragma unroll
        for (int r = 0; r < 16; r++) xq0[r] = xg[(size_t)r * (NG * HH)];
    }

    // ---- W2 diag-sums + corrections from regs ----
    {
        float d0 = wv9[0];
        float d1 = wv9[1] + wv9[3];
        float d2 = wv9[2] + wv9[4] + wv9[6];
        float d3 = wv9[5] + wv9[7];
        float d4 = wv9[8];
        float* wp2 = w2s + gW * 160 + jW;
        wp2[0]   = d0;
        wp2[32]  = d1;
        wp2[64]  = d2;
        wp2[96]  = d3;
        wp2[128] = d4;
        wcs[gW * 32 + jW]       = wv9[2];        // w[0][2]
        wcs[256 + gW * 32 + jW] = wv9[6];        // w[2][0]
    }
    // ---- zero t4s pad columns l2 in {0,1,16,17,18,19} ----
#pragma unroll
    for (int r = 0; r < 3; r++) {                // 768 entries
        int idx = r * 256 + tid;
        int gp  = idx / 6;
        int s   = idx % 6;
        int l2  = (s < 2) ? s : (14 + s);
        t4s[gp * LROW + l2] = 0.f;
    }

    // ---- phase B: direct-global mix, reg-double-buffered j-quarters ----
    float am[8] = {0.f, 0.f, 0.f, 0.f, 0.f, 0.f, 0.f, 0.f};
    if (xact) {
#pragma unroll
        for (int r = 0; r < 16; r++) xq1[r] = xg[(size_t)(16 + r) * (NG * HH)];
        FMAQ(xq0, 0);
#pragma unroll
        for (int r = 0; r < 16; r++) xq0[r] = xg[(size_t)(32 + r) * (NG * HH)];
        FMAQ(xq1, 16);
#pragma unroll
        for (int r = 0; r < 16; r++) xq1[r] = xg[(size_t)(48 + r) * (NG * HH)];
        FMAQ(xq0, 32);
        FMAQ(xq1, 48);
        // scatter t4 slice into conv layout t4s[(g*16+p)*20 + l+2]
#pragma unroll
        for (int pp = 0; pp < 8; pp++) {
            t4s[(gS * 16 + p0 + pp) * LROW + lS + 2] = am[pp];
        }
    }
    __syncthreads();   // the ONLY barrier: t4s/w2s/wcs ready

    // ================= conv phase (verified structure, unchanged) ==========
    const int p  = tid & 15;
    const int jh = tid >> 4;        // 0..15
    const int jb = jh * 2;          // channels j = jb, jb+1

    float acc[NH][2];
#pragma unroll
    for (int n = 0; n < NH; n++) { acc[n][0] = 0.f; acc[n][1] = 0.f; }

    for (int g = 0; g < NG; g++) {
        float row[LROW];
        const float* rp = &t4s[(g * 16 + p) * LROW];
#pragma unroll
        for (int q = 0; q < 5; q++) {
            float4 v = *reinterpret_cast<const float4*>(rp + q * 4);
            row[q * 4 + 0] = v.x; row[q * 4 + 1] = v.y;
            row[q * 4 + 2] = v.z; row[q * 4 + 3] = v.w;
        }
#pragma unroll
        for (int di = 0; di < 5; di++) {
            float2 w = *reinterpret_cast<const float2*>(&w2s[(g * 5 + di) * 32 + jb]);
#pragma unroll
            for (int n = 0; n < NH; n++) {
                float rv = row[n + di];
                acc[n][0] += rv * w.x;
                acc[n][1] += rv * w.y;
            }
        }
        float2 c0 = *reinterpret_cast<const float2*>(&wcs[g * 32 + jb]);
        float2 c1 = *reinterpret_cast<const float2*>(&wcs[256 + g * 32 + jb]);
        float r2 = row[2], r15 = row[15];
        acc[0][0]  -= r2  * c0.x; acc[0][1]  -= r2  * c0.y;
        acc[13][0] -= r15 * c1.x; acc[13][1] -= r15 * c1.y;
    }

    // ---- direct writeout: thread owns channels c = (jb+jj)*16 + p, each a
    //      contiguous 14-float run at out[b][c][o][0..13]; 7 float2 stores.
    //      8B-aligned: (b*512*196 + c*196 + o*14 + 2k) is always even.
    {
        float* ob = out + (size_t)b * 512 * HH + (size_t)o * NH;
#pragma unroll
        for (int jj = 0; jj < 2; jj++) {
            float* cp = ob + (size_t)((jb + jj) * 16 + p) * HH;
#pragma unroll
            for (int k = 0; k < 7; k++) {
                *reinterpret_cast<float2*>(cp + 2 * k) =
                    make_float2(acc[2 * k][jj], acc[2 * k + 1][jj]);
            }
        }
    }
}

extern "C" void kernel_launch(void* const* d_in, const int* in_sizes, int n_in,
                              void* d_out, int out_size, void* d_ws, size_t ws_size,
                              hipStream_t stream) {
    const float* x     = (const float*)d_in[0];
    const float* wconv = (const float*)d_in[1];
    const float* wmix  = (const float*)d_in[2];
    float* out = (float*)d_out;
    (void)d_ws; (void)ws_size;

    // one block per (b, o), XCD-swizzled decode inside the kernel
    fused_kernel<<<NB * NH, 256, 0, stream>>>(x, wconv, wmix, out);
}